// Round 7
// baseline (66.809 us; speedup 1.0000x reference)
//
#include <hip/hip_runtime.h>

// Sinkhorn (eps=0.2, 50 iters), 64x64 images, b=64. Separable banded Gibbs:
// K = G (x) G, G[i,k]=exp(-5(i-k)^2), radius 2 in fp32.
//
// R7: minimum-serialization register-resident version.
//   state: V column-per-lane (lane l = col l, wave w = rows 8w..8w+7 + halos),
//          U row-per-lane (lane = row 8w+(l&7), cols 8(l>>3)-2 .. +9, 12 wide).
//   per iteration: ONE __syncthreads, zero fences, zero shuffles.
//   p1a vert G*V in regs -> p1b transpose via wave-private S0 (write rows
//   8w..8w+7 / read rows 8w+q: same-wave DS is in-order, compiler barrier
//   only) -> horiz conv at 12 cols (halo cols computed redundantly, kills the
//   p2a shuffles) -> p2a horiz U*G in regs -> p2b transpose via parity-
//   double-buffered S1 (the only cross-wave exchange: one __syncthreads;
//   parity removes the WAR-protecting second barrier; __syncthreads' lgkmcnt
//   drain makes parity reuse safe) -> vert conv 12 rows (halo rows redundant).
// Bank check (32 banks, b32): S0w (8w+k+l)%32, S0r (q+8hq+m-4+8w)%32,
// S1w (8w+q+8hq+c)%32, S1r (8w-4+m+l)%32 -- every instruction covers each
// bank exactly twice (2-way b32 = free, m136). Zero conflicts expected.

#define CBAR() asm volatile("" ::: "memory")

__device__ __forceinline__ float frcp_nr(float d) {
    float r = __builtin_amdgcn_rcpf(d);
    return r * fmaf(-d, r, 2.0f);   // 1 Newton step: ~1 ulp
}

// One full Sinkhorn iteration. SW/SR: parity buffer write/read pointers.
#define ITER_BODY(SW, SR)                                                      \
  {                                                                            \
    float W[12], s8[8], R[16];                                                 \
    W[0] = lo ? vh0 : 0.f;  W[1] = lo ? vh1 : 0.f;                             \
    _Pragma("unroll") for (int k = 0; k < 8; ++k) W[k + 2] = vv[k];            \
    W[10] = hi ? vh2 : 0.f; W[11] = hi ? vh3 : 0.f;                            \
    _Pragma("unroll") for (int k = 0; k < 8; ++k)                              \
      s8[k] = fmaf(g2, W[k] + W[k + 4], fmaf(g1, W[k + 1] + W[k + 3], W[k + 2])); \
    _Pragma("unroll") for (int k = 0; k < 8; ++k) pS0w[65 * k] = s8[k];        \
    CBAR();                                                                    \
    _Pragma("unroll") for (int m = 0; m < 16; ++m) R[m] = pS0r[m];             \
    if (hq == 0)  { R[0] = 0.f; R[1] = 0.f; R[2] = 0.f; R[3] = 0.f; }          \
    if (hq == 15) { R[12] = 0.f; R[13] = 0.f; R[14] = 0.f; R[15] = 0.f; }      \
    _Pragma("unroll") for (int j = 0; j < 12; ++j) {                           \
      float o = fmaf(g2, R[j] + R[j + 4], fmaf(g1, R[j + 1] + R[j + 3], R[j + 2])); \
      um[j] = xv[j] * frcp_nr(o + 1e-8f);                                      \
    }                                                                          \
    W[0] = clo ? um[0] : 0.f;  W[1] = clo ? um[1] : 0.f;                       \
    _Pragma("unroll") for (int j = 2; j < 10; ++j) W[j] = um[j];               \
    W[10] = chi ? um[10] : 0.f; W[11] = chi ? um[11] : 0.f;                    \
    _Pragma("unroll") for (int c = 0; c < 8; ++c)                              \
      (SW)[c] = fmaf(g2, W[c] + W[c + 4], fmaf(g1, W[c + 1] + W[c + 3], W[c + 2])); \
    __syncthreads();                                                           \
    float Rv[16], e[12];                                                       \
    _Pragma("unroll") for (int m = 0; m < 16; ++m) Rv[m] = (SR)[65 * m];       \
    if (w == 0) { Rv[0] = 0.f; Rv[1] = 0.f; Rv[2] = 0.f; Rv[3] = 0.f; }        \
    if (w == 7) { Rv[12] = 0.f; Rv[13] = 0.f; Rv[14] = 0.f; Rv[15] = 0.f; }    \
    _Pragma("unroll") for (int k = 0; k < 12; ++k)                             \
      e[k] = fmaf(g2, Rv[k] + Rv[k + 4], fmaf(g1, Rv[k + 1] + Rv[k + 3], Rv[k + 2])); \
    _Pragma("unroll") for (int k = 0; k < 8; ++k)                              \
      vv[k] = yv[k] * frcp_nr(e[k + 2] + 1e-8f);                               \
    vh0 = yh0 * frcp_nr(e[0]  + 1e-8f);                                        \
    vh1 = yh1 * frcp_nr(e[1]  + 1e-8f);                                        \
    vh2 = yh2 * frcp_nr(e[10] + 1e-8f);                                        \
    vh3 = yh3 * frcp_nr(e[11] + 1e-8f);                                        \
  }

extern "C" __global__ void __launch_bounds__(512)
sinkhorn_kernel(const float* __restrict__ x, const float* __restrict__ y,
                const float* __restrict__ cost, const float* __restrict__ kern,
                float* __restrict__ partials)
{
    // [pad 260][S1a 4160][pad 260][S1b 4160][pad 260][S0 4160][wsum 8]
    __shared__ float lds[13268];
    float* const S1a  = lds + 260;
    float* const S1b  = lds + 4680;
    float* const S0   = lds + 9100;
    float* const wsum = lds + 13260;

    const int t  = threadIdx.x;
    const int l  = t & 63;
    const int w  = t >> 6;          // wave 0..7 owns rows [8w, 8w+8)
    const int q  = l & 7;
    const int hq = l >> 3;
    const int rB = 8 * w + q;       // layout-B row
    const int c0 = 8 * hq;          // layout-B col base
    const int b  = blockIdx.x;

    const float g1 = kern[(size_t)64  * 4096];        // e^-5
    const float g2 = kern[(size_t)128 * 4096];        // e^-20
    const float q1 = cost[(size_t)64  * 4096] * g1;   // 1*e^-5
    const float q2 = cost[(size_t)128 * 4096] * g2;   // 4*e^-20

    // loop-invariant LDS pointers (all b32 with immediate offsets)
    float* const pS0w = S0 + 65 * (8 * w) + l;        // p1b writes [+65k]
    const float* const pS0r = S0 + 65 * rB + c0 - 4;  // p1b reads  [+m], 16 wide
    float* const pSaw = S1a + 65 * rB + c0;           // p2b writes [+c]
    const float* const pSar = S1a + 65 * (8 * w - 4) + l; // p2b reads [+65m]
    float* const pSbw = S1b + 65 * rB + c0;
    const float* const pSbr = S1b + 65 * (8 * w - 4) + l;

    const bool lo  = (w > 0),  hi  = (w < 7);
    const bool clo = (hq > 0), chi = (hq < 15);

    // marginals in registers for all 50 iters
    float xv[12], yv[8], yh0, yh1, yh2, yh3;
    {
        const float* xrow = x + (size_t)b * 4096 + 64 * rB;
#pragma unroll
        for (int j = 0; j < 12; ++j) {
            int cc = c0 - 2 + j;                       // col of um[j]
            cc = cc < 0 ? 0 : (cc > 63 ? 63 : cc);     // clamp (value unused OOB)
            xv[j] = xrow[cc];
        }
        const float* yb = y + (size_t)b * 4096 + l;
#pragma unroll
        for (int k = 0; k < 8; ++k) yv[k] = yb[64 * (8 * w + k)];
        yh0 = yb[64 * (lo ? 8 * w - 2 : 0)];
        yh1 = yb[64 * (lo ? 8 * w - 1 : 0)];
        yh2 = yb[64 * (hi ? 8 * w + 8 : 63)];
        yh3 = yb[64 * (hi ? 8 * w + 9 : 63)];
    }

    // state: V column-per-lane (+4 halo rows), U 12-wide row-per-lane
    float vv[8], vh0, vh1, vh2, vh3, um[12];
#pragma unroll
    for (int k = 0; k < 8; ++k) vv[k] = 1.0f / 4096.0f;
    vh0 = vh1 = vh2 = vh3 = 1.0f / 4096.0f;

#pragma unroll 1
    for (int it2 = 0; it2 < 25; ++it2) {
        ITER_BODY(pSaw, pSar)
        ITER_BODY(pSbw, pSbr)
    }

    // ---- distance: sum U o ((G2*V)*G) + sum U o ((G*V)*G2)
    // S0 is wave-private; same-wave DS in-order => no barriers needed here.
    float acc = 0.0f;
    {
        float W[12], s8[8], R[16];
        W[0] = lo ? vh0 : 0.f;  W[1] = lo ? vh1 : 0.f;
#pragma unroll
        for (int k = 0; k < 8; ++k) W[k + 2] = vv[k];
        W[10] = hi ? vh2 : 0.f; W[11] = hi ? vh3 : 0.f;

        // round 1: vertical q-taps, horizontal g-taps
#pragma unroll
        for (int k = 0; k < 8; ++k)
            s8[k] = fmaf(q2, W[k] + W[k + 4], q1 * (W[k + 1] + W[k + 3]));
#pragma unroll
        for (int k = 0; k < 8; ++k) pS0w[65 * k] = s8[k];
        CBAR();
#pragma unroll
        for (int m = 0; m < 16; ++m) R[m] = pS0r[m];
        if (hq == 0)  { R[0] = 0.f; R[1] = 0.f; R[2] = 0.f; R[3] = 0.f; }
        if (hq == 15) { R[12] = 0.f; R[13] = 0.f; R[14] = 0.f; R[15] = 0.f; }
#pragma unroll
        for (int j = 2; j < 10; ++j) {
            float o = fmaf(g2, R[j] + R[j + 4], fmaf(g1, R[j + 1] + R[j + 3], R[j + 2]));
            acc = fmaf(um[j], o, acc);
        }
        CBAR();   // keep round-1 reads ordered before round-2 writes (same wave)

        // round 2: vertical g-taps, horizontal q-taps
#pragma unroll
        for (int k = 0; k < 8; ++k)
            s8[k] = fmaf(g2, W[k] + W[k + 4], fmaf(g1, W[k + 1] + W[k + 3], W[k + 2]));
#pragma unroll
        for (int k = 0; k < 8; ++k) pS0w[65 * k] = s8[k];
        CBAR();
#pragma unroll
        for (int m = 0; m < 16; ++m) R[m] = pS0r[m];
        if (hq == 0)  { R[0] = 0.f; R[1] = 0.f; R[2] = 0.f; R[3] = 0.f; }
        if (hq == 15) { R[12] = 0.f; R[13] = 0.f; R[14] = 0.f; R[15] = 0.f; }
#pragma unroll
        for (int j = 2; j < 10; ++j) {
            float o = fmaf(q2, R[j] + R[j + 4], q1 * (R[j + 1] + R[j + 3]));
            acc = fmaf(um[j], o, acc);
        }
    }

    // deterministic reduction: wave shfl tree, then fixed-order 8-way sum
#pragma unroll
    for (int off = 32; off > 0; off >>= 1)
        acc += __shfl_down(acc, off, 64);
    if (l == 0) wsum[w] = acc;
    __syncthreads();
    if (t == 0) {
        partials[b] = ((wsum[0] + wsum[1]) + (wsum[2] + wsum[3]))
                    + ((wsum[4] + wsum[5]) + (wsum[6] + wsum[7]));
    }
}

extern "C" __global__ void __launch_bounds__(64)
reduce_kernel(const float* __restrict__ partials, float* __restrict__ out)
{
    int t = threadIdx.x;
    float v = partials[t];
#pragma unroll
    for (int off = 32; off > 0; off >>= 1)
        v += __shfl_down(v, off, 64);
    if (t == 0) out[0] = v;
}

extern "C" void kernel_launch(void* const* d_in, const int* in_sizes, int n_in,
                              void* d_out, int out_size, void* d_ws, size_t ws_size,
                              hipStream_t stream)
{
    const float* x    = (const float*)d_in[0];
    const float* y    = (const float*)d_in[1];
    const float* cost = (const float*)d_in[2];
    const float* kern = (const float*)d_in[3];
    float* partials   = (float*)d_ws;   // 64 floats

    sinkhorn_kernel<<<64, 512, 0, stream>>>(x, y, cost, kern, partials);
    reduce_kernel<<<1, 64, 0, stream>>>(partials, (float*)d_out);
}